// Round 5
// baseline (725.366 us; speedup 1.0000x reference)
//
#include <hip/hip_runtime.h>
#include <hip/hip_fp16.h>

typedef _Float16 f16x8 __attribute__((ext_vector_type(8)));
typedef float f32x4 __attribute__((ext_vector_type(4)));

// LeNet C3 connection table: input channel ii feeds CONN[ii][j] with weight[j][ii].
__device__ constexpr int CONN[6][10] = {
    {0, 4, 5, 6, 9, 10, 11, 12, 14, 15},
    {0, 1, 5, 6, 7, 10, 11, 12, 13, 15},
    {0, 1, 2, 6, 7, 8, 11, 13, 14, 15},
    {1, 2, 3, 6, 7, 8, 9, 12, 14, 15},
    {2, 3, 4, 7, 8, 9, 10, 12, 13, 15},
    {3, 4, 5, 8, 9, 10, 11, 13, 14, 15}};

__device__ __forceinline__ f16x8 u4_to_h8(uint4 u) { f16x8 r; __builtin_memcpy(&r, &u, 16); return r; }

// Build the B operand panel in MFMA fragment order.
// K' = 256: k = ks*32 + kb*8 + j ; slice s = ks*4+kb -> (ii = s/5, r = s%5), kx = j.
// B[k][n] = w_full[n][ii][r][kx]  (zero if j>=5, s>=30, or n not in CONN[ii]).
// Layout: halves at B[(ks*64 + lane)*8 + j]; lane gives (n = lane&15, kb = lane>>4).
__global__ void prep_B(const float* __restrict__ w, unsigned short* __restrict__ B) {
    int t = blockIdx.x * 256 + threadIdx.x;   // 0..4095 half index
    if (t >= 4096) return;
    int j    = t & 7;
    int lane = (t >> 3) & 63;
    int ks   = t >> 9;
    int n  = lane & 15;
    int kb = lane >> 4;
    int s  = ks * 4 + kb;
    float val = 0.f;
    if (s < 30 && j < 5) {
        int ii = s / 5, r = s % 5;
        for (int jj = 0; jj < 10; ++jj)
            if (CONN[ii][jj] == n)
                val = w[jj * 150 + ii * 25 + r * 5 + j];
    }
    __half h = __float2half(val);
    unsigned short u; __builtin_memcpy(&u, &h, 2);
    B[t] = u;
}

// Block: 64y x 64x output tile, 4 waves (wave w: rows Y0+16w..+15), all 16 ch.
// LDS: fp16 tile 6ch x 68row x 76 halves, pitch 152 B (38 dw: 16 lanes -> 32
// distinct banks for b64 reads, zero conflict; rows 8B-aligned).
__global__ __launch_bounds__(256, 2) void c3_mfma(
    const float* __restrict__ x, const unsigned short* __restrict__ Bw,
    const float* __restrict__ bias, float* __restrict__ out)
{
    __shared__ char s_raw[6 * 68 * 152];   // 62016 B

    const int tid = threadIdx.x;
    const int X0 = blockIdx.x * 64;
    const int Y0 = blockIdx.y * 64;
    const int n  = blockIdx.z;
    const float* xin = x + (size_t)n * 6 * 65536;

    // ---- stage 6ch x 68row x 72col f32 -> fp16 LDS (18 float4 per row) ----
    for (int i = tid; i < 6 * 68 * 18; i += 256) {
        int c4  = i % 18;
        int t   = i / 18;
        int row = t % 68;
        int ch  = t / 68;
        int gr  = Y0 + row; if (gr > 255) gr = 255;          // OOB -> garbage feeding only discarded/zero-weight terms
        int gc4 = (X0 >> 2) + c4; if (gc4 > 63) gc4 = 63;
        float4 v = *reinterpret_cast<const float4*>(xin + (size_t)ch * 65536 + gr * 256 + gc4 * 4);
        __half2 lo = __floats2half2_rn(v.x, v.y);
        __half2 hi = __floats2half2_rn(v.z, v.w);
        uint2 u; __builtin_memcpy(&u.x, &lo, 4); __builtin_memcpy(&u.y, &hi, 4);
        *reinterpret_cast<uint2*>(s_raw + (ch * 68 + row) * 152 + c4 * 8) = u;
    }
    __syncthreads();

    const int lane = tid & 63;
    const int wv   = tid >> 6;
    const int m    = lane & 15;   // A-row (pixel y offset) AND C-col (channel)
    const int kb   = lane >> 4;   // A/B k-block AND C row-block

    // ---- B fragments: 8 K-steps x 16B per lane (L2-hot) ----
    f16x8 bfr[8];
    #pragma unroll
    for (int ks = 0; ks < 8; ++ks)
        bfr[ks] = u4_to_h8(*reinterpret_cast<const uint4*>(Bw + (ks * 64 + lane) * 8));

    // ---- per-lane A window base addresses (bytes into LDS) ----
    int abase[8];
    #pragma unroll
    for (int ks = 0; ks < 8; ++ks) {
        int s = ks * 4 + kb;
        if (s >= 30) s = 0;               // dummy slices: B is zero there
        int ii = s / 5, r = s - ii * 5;
        abase[ks] = (ii * 68 + 16 * wv + m + r) * 152;
    }

    const float bb = bias[m] * (m < 6 ? 3.0f : (m < 15 ? 4.0f : 6.0f));

    const int gy0 = Y0 + 16 * wv + kb * 4;
    float* const outn = out + (size_t)n * 16 * 63504 + (size_t)m * 63504;

    #pragma unroll 4
    for (int a = 0; a < 64; a += 4) {     // each group: 4 output x = X0+a+0..3
        // load 8 windows (halves a..a+7 of each slice), 8B-aligned
        f16x8 W[8];
        #pragma unroll
        for (int ks = 0; ks < 8; ++ks) {
            const uint2* p = reinterpret_cast<const uint2*>(s_raw + abase[ks] + 2 * a);
            uint2 d0 = p[0], d1 = p[1];
            uint4 u = make_uint4(d0.x, d0.y, d1.x, d1.y);
            W[ks] = u4_to_h8(u);
        }

        f32x4 acc0 = {0.f, 0.f, 0.f, 0.f}, acc1 = acc0, acc2 = acc0, acc3 = acc0;
        #pragma unroll
        for (int ks = 0; ks < 8; ++ks) {
            f16x8 w0 = W[ks];
            f16x8 w1 = __builtin_shufflevector(w0, w0, 1, 2, 3, 4, 5, 6, 7, 0);
            f16x8 w2 = __builtin_shufflevector(w0, w0, 2, 3, 4, 5, 6, 7, 0, 1);
            f16x8 w3 = __builtin_shufflevector(w0, w0, 3, 4, 5, 6, 7, 0, 1, 2);
            acc0 = __builtin_amdgcn_mfma_f32_16x16x32_f16(w0, bfr[ks], acc0, 0, 0, 0);
            acc1 = __builtin_amdgcn_mfma_f32_16x16x32_f16(w1, bfr[ks], acc1, 0, 0, 0);
            acc2 = __builtin_amdgcn_mfma_f32_16x16x32_f16(w2, bfr[ks], acc2, 0, 0, 0);
            acc3 = __builtin_amdgcn_mfma_f32_16x16x32_f16(w3, bfr[ks], acc3, 0, 0, 0);
        }

        const int ga = X0 + a;
        if (ga < 252) {
            #pragma unroll
            for (int q = 0; q < 4; ++q) {
                int gy = gy0 + q;
                if (gy < 252) {
                    f32x4 v = {acc0[q] + bb, acc1[q] + bb, acc2[q] + bb, acc3[q] + bb};
                    __builtin_nontemporal_store(v,
                        reinterpret_cast<f32x4*>(outn + (size_t)gy * 252 + ga));
                }
            }
        }
    }
}

extern "C" void kernel_launch(void* const* d_in, const int* in_sizes, int n_in,
                              void* d_out, int out_size, void* d_ws, size_t ws_size,
                              hipStream_t stream) {
    const float* x    = (const float*)d_in[0];  // (64,6,256,256)
    const float* w    = (const float*)d_in[1];  // (10,6,5,5)
    const float* bias = (const float*)d_in[2];  // (1,16,1,1)
    float* out = (float*)d_out;                 // (64,16,252,252)
    unsigned short* Bw = (unsigned short*)d_ws; // 4096 halves (8 KB) MFMA B panel

    hipLaunchKernelGGL(prep_B, dim3(16), dim3(256), 0, stream, w, Bw);
    dim3 grid(4, 4, 64);
    hipLaunchKernelGGL(c3_mfma, grid, dim3(256), 0, stream, x, Bw, bias, out);
}

// Round 6
// 245.910 us; speedup vs baseline: 2.9497x; 2.9497x over previous
//
#include <hip/hip_runtime.h>
#include <hip/hip_fp16.h>

typedef _Float16 f16x8 __attribute__((ext_vector_type(8)));
typedef float f32x4 __attribute__((ext_vector_type(4)));

// LeNet C3 connection table: input channel ii feeds CONN[ii][j] with weight[j][ii].
__device__ constexpr int CONN[6][10] = {
    {0, 4, 5, 6, 9, 10, 11, 12, 14, 15},
    {0, 1, 5, 6, 7, 10, 11, 12, 13, 15},
    {0, 1, 2, 6, 7, 8, 11, 13, 14, 15},
    {1, 2, 3, 6, 7, 8, 9, 12, 14, 15},
    {2, 3, 4, 7, 8, 9, 10, 12, 13, 15},
    {3, 4, 5, 8, 9, 10, 11, 13, 14, 15}};

__device__ __forceinline__ f16x8 u4_to_h8(uint4 u) { f16x8 r; __builtin_memcpy(&r, &u, 16); return r; }

// Build the B operand panel in MFMA fragment order.
// K' = 256: k = ks*32 + kb*8 + j ; slice s = ks*4+kb -> (ii = s/5, r = s%5), kx = j.
// B[k][n] = w_full[n][ii][r][kx]  (zero if j>=5, s>=30, or n not in CONN[ii]).
// Layout: halves at B[(ks*64 + lane)*8 + j]; lane gives (n = lane&15, kb = lane>>4).
__global__ void prep_B(const float* __restrict__ w, unsigned short* __restrict__ B) {
    int t = blockIdx.x * 256 + threadIdx.x;   // 0..4095 half index
    if (t >= 4096) return;
    int j    = t & 7;
    int lane = (t >> 3) & 63;
    int ks   = t >> 9;
    int n  = lane & 15;
    int kb = lane >> 4;
    int s  = ks * 4 + kb;
    float val = 0.f;
    if (s < 30 && j < 5) {
        int ii = s / 5, r = s % 5;
        for (int jj = 0; jj < 10; ++jj)
            if (CONN[ii][jj] == n)
                val = w[jj * 150 + ii * 25 + r * 5 + j];
    }
    __half h = __float2half(val);
    unsigned short u; __builtin_memcpy(&u, &h, 2);
    B[t] = u;
}

// Block: 64x x 32y output tile, 4 waves. Wave wv: y-block (wv&1)*16, x-half (wv>>1)*32.
// LDS: fp16 tile 6ch x 36row x 76 halves, pitch 152 B -> 33 KB, 4 blocks/CU.
__global__ __launch_bounds__(256, 4) void c3_mfma(
    const float* __restrict__ x, const unsigned short* __restrict__ Bw,
    const float* __restrict__ bias, float* __restrict__ out)
{
    __shared__ char s_raw[6 * 36 * 152];   // 32832 B

    const int tid = threadIdx.x;
    const int X0 = blockIdx.x * 64;
    const int Y0 = blockIdx.y * 32;
    const int n  = blockIdx.z;
    const float* xin = x + (size_t)n * 6 * 65536;

    // ---- stage 6ch x 36row x 72col f32 -> fp16 LDS (18 float4 per row) ----
    for (int i = tid; i < 6 * 36 * 18; i += 256) {
        int c4  = i % 18;
        int t   = i / 18;
        int row = t % 36;
        int ch  = t / 36;
        int gr  = Y0 + row; if (gr > 255) gr = 255;          // OOB -> garbage feeding only discarded outputs
        int gc4 = (X0 >> 2) + c4; if (gc4 > 63) gc4 = 63;
        float4 v = *reinterpret_cast<const float4*>(xin + (size_t)ch * 65536 + gr * 256 + gc4 * 4);
        __half2 lo = __floats2half2_rn(v.x, v.y);
        __half2 hi = __floats2half2_rn(v.z, v.w);
        uint2 u; __builtin_memcpy(&u.x, &lo, 4); __builtin_memcpy(&u.y, &hi, 4);
        *reinterpret_cast<uint2*>(s_raw + (ch * 36 + row) * 152 + c4 * 8) = u;
    }
    __syncthreads();

    const int lane = tid & 63;
    const int wv   = tid >> 6;
    const int yb   = (wv & 1) * 16;    // wave's y-block within tile
    const int xh   = (wv >> 1) * 32;   // wave's x-half within tile
    const int m    = lane & 15;        // A-row (y offset) AND C-col (channel)
    const int kb   = lane >> 4;        // A/B k-block AND C row-block

    // ---- B fragments: 8 K-steps x 16B per lane (L2-hot) ----
    f16x8 bfr[8];
    #pragma unroll
    for (int ks = 0; ks < 8; ++ks)
        bfr[ks] = u4_to_h8(*reinterpret_cast<const uint4*>(Bw + (ks * 64 + lane) * 8));

    // ---- per-lane A window base addresses (bytes into LDS) ----
    int abase[8];
    #pragma unroll
    for (int ks = 0; ks < 8; ++ks) {
        int s = ks * 4 + kb;
        if (s >= 30) s = 0;               // dummy slices: B is zero there
        int ii = s / 5, r = s - ii * 5;
        abase[ks] = (ii * 36 + yb + m + r) * 152 + xh * 2;
    }

    const float bb = bias[m] * (m < 6 ? 3.0f : (m < 15 ? 4.0f : 6.0f));

    const int gy0 = Y0 + yb + kb * 4;
    float* const outn = out + (size_t)n * 16 * 63504 + (size_t)m * 63504;

    #pragma unroll 2
    for (int a = 0; a < 32; a += 4) {     // each group: 4 output x = X0+xh+a+0..3
        // load 8 windows (halves a..a+7 of each slice), 8B-aligned
        f16x8 W[8];
        #pragma unroll
        for (int ks = 0; ks < 8; ++ks) {
            const uint2* p = reinterpret_cast<const uint2*>(s_raw + abase[ks] + 2 * a);
            uint2 d0 = p[0], d1 = p[1];
            uint4 u = make_uint4(d0.x, d0.y, d1.x, d1.y);
            W[ks] = u4_to_h8(u);
        }

        f32x4 acc0 = {0.f, 0.f, 0.f, 0.f}, acc1 = acc0, acc2 = acc0, acc3 = acc0;
        #pragma unroll
        for (int ks = 0; ks < 8; ++ks) {
            f16x8 w0 = W[ks];
            f16x8 w1 = __builtin_shufflevector(w0, w0, 1, 2, 3, 4, 5, 6, 7, 0);
            f16x8 w2 = __builtin_shufflevector(w0, w0, 2, 3, 4, 5, 6, 7, 0, 1);
            f16x8 w3 = __builtin_shufflevector(w0, w0, 3, 4, 5, 6, 7, 0, 1, 2);
            acc0 = __builtin_amdgcn_mfma_f32_16x16x32_f16(w0, bfr[ks], acc0, 0, 0, 0);
            acc1 = __builtin_amdgcn_mfma_f32_16x16x32_f16(w1, bfr[ks], acc1, 0, 0, 0);
            acc2 = __builtin_amdgcn_mfma_f32_16x16x32_f16(w2, bfr[ks], acc2, 0, 0, 0);
            acc3 = __builtin_amdgcn_mfma_f32_16x16x32_f16(w3, bfr[ks], acc3, 0, 0, 0);
        }

        const int ga = X0 + xh + a;
        if (ga < 252) {
            #pragma unroll
            for (int q = 0; q < 4; ++q) {
                int gy = gy0 + q;
                if (gy < 252) {
                    f32x4 v = {acc0[q] + bb, acc1[q] + bb, acc2[q] + bb, acc3[q] + bb};
                    *reinterpret_cast<f32x4*>(outn + (size_t)gy * 252 + ga) = v;
                }
            }
        }
    }
}

extern "C" void kernel_launch(void* const* d_in, const int* in_sizes, int n_in,
                              void* d_out, int out_size, void* d_ws, size_t ws_size,
                              hipStream_t stream) {
    const float* x    = (const float*)d_in[0];  // (64,6,256,256)
    const float* w    = (const float*)d_in[1];  // (10,6,5,5)
    const float* bias = (const float*)d_in[2];  // (1,16,1,1)
    float* out = (float*)d_out;                 // (64,16,252,252)
    unsigned short* Bw = (unsigned short*)d_ws; // 4096 halves (8 KB) MFMA B panel

    hipLaunchKernelGGL(prep_B, dim3(16), dim3(256), 0, stream, w, Bw);
    dim3 grid(4, 8, 64);
    hipLaunchKernelGGL(c3_mfma, grid, dim3(256), 0, stream, x, Bw, bias, out);
}

// Round 7
// 210.833 us; speedup vs baseline: 3.4405x; 1.1664x over previous
//
#include <hip/hip_runtime.h>
#include <hip/hip_fp16.h>

typedef _Float16 f16x8 __attribute__((ext_vector_type(8)));
typedef float f32x4 __attribute__((ext_vector_type(4)));

// LeNet C3 connection table: input channel ii feeds CONN[ii][j] with weight[j][ii].
__device__ constexpr int CONN[6][10] = {
    {0, 4, 5, 6, 9, 10, 11, 12, 14, 15},
    {0, 1, 5, 6, 7, 10, 11, 12, 13, 15},
    {0, 1, 2, 6, 7, 8, 11, 13, 14, 15},
    {1, 2, 3, 6, 7, 8, 9, 12, 14, 15},
    {2, 3, 4, 7, 8, 9, 10, 12, 13, 15},
    {3, 4, 5, 8, 9, 10, 11, 13, 14, 15}};

__device__ __forceinline__ f16x8 u4_to_h8(uint4 u) { f16x8 r; __builtin_memcpy(&r, &u, 16); return r; }

// Build the B operand panel in MFMA fragment order.
// K' = 256: k = ks*32 + kb*8 + j ; slice s = ks*4+kb -> (ii = s/5, r = s%5), kx = j.
// B[k][n] = w_full[n][ii][r][kx]  (zero if j>=5, s>=30, or n not in CONN[ii]).
// Layout: halves at B[(ks*64 + lane)*8 + j]; lane gives (n = lane&15, kb = lane>>4).
__global__ void prep_B(const float* __restrict__ w, unsigned short* __restrict__ B) {
    int t = blockIdx.x * 256 + threadIdx.x;   // 0..4095 half index
    if (t >= 4096) return;
    int j    = t & 7;
    int lane = (t >> 3) & 63;
    int ks   = t >> 9;
    int n  = lane & 15;
    int kb = lane >> 4;
    int s  = ks * 4 + kb;
    float val = 0.f;
    if (s < 30 && j < 5) {
        int ii = s / 5, r = s % 5;
        for (int jj = 0; jj < 10; ++jj)
            if (CONN[ii][jj] == n)
                val = w[jj * 150 + ii * 25 + r * 5 + j];
    }
    __half h = __float2half(val);
    unsigned short u; __builtin_memcpy(&u, &h, 2);
    B[t] = u;
}

// Block: 64x x 32y output tile, 4 waves. Wave wv: y-block (wv&1)*16, x-half (wv>>1)*32.
// LDS: fp16 tile 6ch x 36row x 76 halves, pitch 152 B -> 33 KB.
// Store path: buffer 4 x-groups (16 cols) of accumulators, then per output row
// issue 4x 16B stores back-to-back into the same 64B line -> L2 merges, no
// partial-line eviction (R6's 2x write amplification).
__global__ __launch_bounds__(256, 3) void c3_mfma(
    const float* __restrict__ x, const unsigned short* __restrict__ Bw,
    const float* __restrict__ bias, float* __restrict__ out)
{
    __shared__ char s_raw[6 * 36 * 152];   // 32832 B

    const int tid = threadIdx.x;
    const int X0 = blockIdx.x * 64;
    const int Y0 = blockIdx.y * 32;
    const int n  = blockIdx.z;
    const float* xin = x + (size_t)n * 6 * 65536;

    // ---- stage 6ch x 36row x 72col f32 -> fp16 LDS (18 float4 per row) ----
    for (int i = tid; i < 6 * 36 * 18; i += 256) {
        int c4  = i % 18;
        int t   = i / 18;
        int row = t % 36;
        int ch  = t / 36;
        int gr  = Y0 + row; if (gr > 255) gr = 255;          // OOB -> garbage feeding only discarded outputs
        int gc4 = (X0 >> 2) + c4; if (gc4 > 63) gc4 = 63;
        float4 v = *reinterpret_cast<const float4*>(xin + (size_t)ch * 65536 + gr * 256 + gc4 * 4);
        __half2 lo = __floats2half2_rn(v.x, v.y);
        __half2 hi = __floats2half2_rn(v.z, v.w);
        uint2 u; __builtin_memcpy(&u.x, &lo, 4); __builtin_memcpy(&u.y, &hi, 4);
        *reinterpret_cast<uint2*>(s_raw + (ch * 36 + row) * 152 + c4 * 8) = u;
    }
    __syncthreads();

    const int lane = tid & 63;
    const int wv   = tid >> 6;
    const int yb   = (wv & 1) * 16;    // wave's y-block within tile
    const int xh   = (wv >> 1) * 32;   // wave's x-half within tile
    const int m    = lane & 15;        // A-row (y offset) AND C-col (channel)
    const int kb   = lane >> 4;        // A/B k-block AND C row-block

    // ---- B fragments: 8 K-steps x 16B per lane (L2-hot) ----
    f16x8 bfr[8];
    #pragma unroll
    for (int ks = 0; ks < 8; ++ks)
        bfr[ks] = u4_to_h8(*reinterpret_cast<const uint4*>(Bw + (ks * 64 + lane) * 8));

    // ---- per-lane A window base addresses (bytes into LDS) ----
    int abase[8];
    #pragma unroll
    for (int ks = 0; ks < 8; ++ks) {
        int s = ks * 4 + kb;
        if (s >= 30) s = 0;               // dummy slices: B is zero there
        int ii = s / 5, r = s - ii * 5;
        abase[ks] = (ii * 36 + yb + m + r) * 152 + xh * 2;
    }

    const float bb = bias[m] * (m < 6 ? 3.0f : (m < 15 ? 4.0f : 6.0f));

    const int gy0 = Y0 + yb + kb * 4;
    float* const outn = out + (size_t)n * 16 * 63504 + (size_t)m * 63504;

    #pragma unroll 1
    for (int t = 0; t < 2; ++t) {         // two 16-col runs per 32-col wave strip
        f32x4 accb[4][4];                  // [g][x-rot]; components = q (row)

        #pragma unroll
        for (int g = 0; g < 4; ++g) {
            const int a = t * 16 + g * 4;  // x offset within wave strip
            f32x4 acc0 = {0.f, 0.f, 0.f, 0.f}, acc1 = acc0, acc2 = acc0, acc3 = acc0;
            #pragma unroll
            for (int ks = 0; ks < 8; ++ks) {
                const uint2* p = reinterpret_cast<const uint2*>(s_raw + abase[ks] + 2 * a);
                uint2 d0 = p[0], d1 = p[1];
                uint4 u = make_uint4(d0.x, d0.y, d1.x, d1.y);
                f16x8 w0 = u4_to_h8(u);
                f16x8 w1 = __builtin_shufflevector(w0, w0, 1, 2, 3, 4, 5, 6, 7, 0);
                f16x8 w2 = __builtin_shufflevector(w0, w0, 2, 3, 4, 5, 6, 7, 0, 1);
                f16x8 w3 = __builtin_shufflevector(w0, w0, 3, 4, 5, 6, 7, 0, 1, 2);
                acc0 = __builtin_amdgcn_mfma_f32_16x16x32_f16(w0, bfr[ks], acc0, 0, 0, 0);
                acc1 = __builtin_amdgcn_mfma_f32_16x16x32_f16(w1, bfr[ks], acc1, 0, 0, 0);
                acc2 = __builtin_amdgcn_mfma_f32_16x16x32_f16(w2, bfr[ks], acc2, 0, 0, 0);
                acc3 = __builtin_amdgcn_mfma_f32_16x16x32_f16(w3, bfr[ks], acc3, 0, 0, 0);
            }
            accb[g][0] = acc0; accb[g][1] = acc1; accb[g][2] = acc2; accb[g][3] = acc3;
        }

        // ---- store: per row q, 4x 16B into one 64B line, back-to-back ----
        const int gx = X0 + xh + t * 16;
        #pragma unroll
        for (int q = 0; q < 4; ++q) {
            const int gy = gy0 + q;
            if (gy < 252) {
                float* rp = outn + (size_t)gy * 252 + gx;
                #pragma unroll
                for (int g = 0; g < 4; ++g) {
                    if (gx + g * 4 < 252) {
                        f32x4 v = {accb[g][0][q] + bb, accb[g][1][q] + bb,
                                   accb[g][2][q] + bb, accb[g][3][q] + bb};
                        *reinterpret_cast<f32x4*>(rp + g * 4) = v;
                    }
                }
            }
        }
    }
}

extern "C" void kernel_launch(void* const* d_in, const int* in_sizes, int n_in,
                              void* d_out, int out_size, void* d_ws, size_t ws_size,
                              hipStream_t stream) {
    const float* x    = (const float*)d_in[0];  // (64,6,256,256)
    const float* w    = (const float*)d_in[1];  // (10,6,5,5)
    const float* bias = (const float*)d_in[2];  // (1,16,1,1)
    float* out = (float*)d_out;                 // (64,16,252,252)
    unsigned short* Bw = (unsigned short*)d_ws; // 4096 halves (8 KB) MFMA B panel

    hipLaunchKernelGGL(prep_B, dim3(16), dim3(256), 0, stream, w, Bw);
    dim3 grid(4, 8, 64);
    hipLaunchKernelGGL(c3_mfma, grid, dim3(256), 0, stream, x, Bw, bias, out);
}

// Round 8
// 178.988 us; speedup vs baseline: 4.0526x; 1.1779x over previous
//
#include <hip/hip_runtime.h>
#include <hip/hip_fp16.h>

typedef _Float16 f16x8 __attribute__((ext_vector_type(8)));
typedef float f32x4 __attribute__((ext_vector_type(4)));

// LeNet C3 connection table: input channel ii feeds CONN[ii][j] with weight[j][ii].
__device__ constexpr int CONN[6][10] = {
    {0, 4, 5, 6, 9, 10, 11, 12, 14, 15},
    {0, 1, 5, 6, 7, 10, 11, 12, 13, 15},
    {0, 1, 2, 6, 7, 8, 11, 13, 14, 15},
    {1, 2, 3, 6, 7, 8, 9, 12, 14, 15},
    {2, 3, 4, 7, 8, 9, 10, 12, 13, 15},
    {3, 4, 5, 8, 9, 10, 11, 13, 14, 15}};

__device__ __forceinline__ f16x8 u4_to_h8(uint4 u) { f16x8 r; __builtin_memcpy(&r, &u, 16); return r; }

// Build the B operand panel in MFMA fragment order.
// K' = 256: k = ks*32 + kb*8 + j ; slice s = ks*4+kb -> (ii = s/5, r = s%5), kx = j.
// B[k][n] = w_full[n][ii][r][kx]  (zero if j>=5, s>=30, or n not in CONN[ii]).
__global__ void prep_B(const float* __restrict__ w, unsigned short* __restrict__ B) {
    int t = blockIdx.x * 256 + threadIdx.x;   // 0..4095 half index
    if (t >= 4096) return;
    int j    = t & 7;
    int lane = (t >> 3) & 63;
    int ks   = t >> 9;
    int n  = lane & 15;
    int kb = lane >> 4;
    int s  = ks * 4 + kb;
    float val = 0.f;
    if (s < 30 && j < 5) {
        int ii = s / 5, r = s % 5;
        for (int jj = 0; jj < 10; ++jj)
            if (CONN[ii][jj] == n)
                val = w[jj * 150 + ii * 25 + r * 5 + j];
    }
    __half h = __float2half(val);
    unsigned short u; __builtin_memcpy(&u, &h, 2);
    B[t] = u;
}

// Block: 64x x 32y output tile, 4 waves. Wave wv: y-block (wv&1)*16, x-half (wv>>1)*32.
// LDS: fp16 input tile (33 KB) + f32 transpose chunk buffer (18 KB).
// Epilogue: accumulators -> s_out (8 rows x 16ch x 32x per chunk) -> contiguous
// f32x4 global stores (full 64B lines, one transaction each). Kills R5-R7's
// partial-line store-transaction bottleneck.
__global__ __launch_bounds__(256, 3) void c3_mfma(
    const float* __restrict__ x, const unsigned short* __restrict__ Bw,
    const float* __restrict__ bias, float* __restrict__ out)
{
    __shared__ char  s_raw[6 * 36 * 152];     // 32832 B fp16 input tile
    __shared__ float s_out[8 * 16 * 36];      // 18432 B f32 chunk buffer

    const int tid = threadIdx.x;
    const int X0 = blockIdx.x * 64;
    const int Y0 = blockIdx.y * 32;
    const int n  = blockIdx.z;
    const float* xin = x + (size_t)n * 6 * 65536;

    // ---- stage 6ch x 36row x 72col f32 -> fp16 LDS (18 float4 per row) ----
    for (int i = tid; i < 6 * 36 * 18; i += 256) {
        int c4  = i % 18;
        int t   = i / 18;
        int row = t % 36;
        int ch  = t / 36;
        int gr  = Y0 + row; if (gr > 255) gr = 255;          // OOB -> garbage feeding only discarded outputs
        int gc4 = (X0 >> 2) + c4; if (gc4 > 63) gc4 = 63;
        float4 v = *reinterpret_cast<const float4*>(xin + (size_t)ch * 65536 + gr * 256 + gc4 * 4);
        __half2 lo = __floats2half2_rn(v.x, v.y);
        __half2 hi = __floats2half2_rn(v.z, v.w);
        uint2 u; __builtin_memcpy(&u.x, &lo, 4); __builtin_memcpy(&u.y, &hi, 4);
        *reinterpret_cast<uint2*>(s_raw + (ch * 36 + row) * 152 + c4 * 8) = u;
    }
    __syncthreads();

    const int lane = tid & 63;
    const int wv   = tid >> 6;
    const int yb   = (wv & 1) * 16;    // wave's y-block within tile
    const int xh   = (wv >> 1) * 32;   // wave's x-half within tile
    const int m    = lane & 15;        // A-row (y offset) AND C-col (channel)
    const int kb   = lane >> 4;        // A/B k-block AND C row-block

    // ---- B fragments: 8 K-steps x 16B per lane (L2-hot) ----
    f16x8 bfr[8];
    #pragma unroll
    for (int ks = 0; ks < 8; ++ks)
        bfr[ks] = u4_to_h8(*reinterpret_cast<const uint4*>(Bw + (ks * 64 + lane) * 8));

    // ---- per-lane A window base addresses (bytes into LDS) ----
    int abase[8];
    #pragma unroll
    for (int ks = 0; ks < 8; ++ks) {
        int s = ks * 4 + kb;
        if (s >= 30) s = 0;               // dummy slices: B is zero there
        int ii = s / 5, r = s - ii * 5;
        abase[ks] = (ii * 36 + yb + m + r) * 152 + xh * 2;
    }

    const float bb = bias[m] * (m < 6 ? 3.0f : (m < 15 ? 4.0f : 6.0f));
    const int mychunk = (wv & 1) * 2 + (kb >> 1);   // which 8-row chunk this lane's rows fall in
    const int yqb     = (kb & 1) * 4;               // row offset within chunk
    const int xb0     = (wv >> 1) * 16;             // x offset within chunk buffer

    #pragma unroll 1
    for (int t = 0; t < 2; ++t) {         // two 16-col runs per 32-col wave strip
        f32x4 accb[4][4];                  // [g][x-rot]; components = q (row)

        #pragma unroll
        for (int g = 0; g < 4; ++g) {
            const int a = t * 16 + g * 4;  // x offset within wave strip
            f32x4 acc0 = {0.f, 0.f, 0.f, 0.f}, acc1 = acc0, acc2 = acc0, acc3 = acc0;
            #pragma unroll
            for (int ks = 0; ks < 8; ++ks) {
                const uint2* p = reinterpret_cast<const uint2*>(s_raw + abase[ks] + 2 * a);
                uint2 d0 = p[0], d1 = p[1];
                uint4 u = make_uint4(d0.x, d0.y, d1.x, d1.y);
                f16x8 w0 = u4_to_h8(u);
                f16x8 w1 = __builtin_shufflevector(w0, w0, 1, 2, 3, 4, 5, 6, 7, 0);
                f16x8 w2 = __builtin_shufflevector(w0, w0, 2, 3, 4, 5, 6, 7, 0, 1);
                f16x8 w3 = __builtin_shufflevector(w0, w0, 3, 4, 5, 6, 7, 0, 1, 2);
                acc0 = __builtin_amdgcn_mfma_f32_16x16x32_f16(w0, bfr[ks], acc0, 0, 0, 0);
                acc1 = __builtin_amdgcn_mfma_f32_16x16x32_f16(w1, bfr[ks], acc1, 0, 0, 0);
                acc2 = __builtin_amdgcn_mfma_f32_16x16x32_f16(w2, bfr[ks], acc2, 0, 0, 0);
                acc3 = __builtin_amdgcn_mfma_f32_16x16x32_f16(w3, bfr[ks], acc3, 0, 0, 0);
            }
            accb[g][0] = acc0; accb[g][1] = acc1; accb[g][2] = acc2; accb[g][3] = acc3;
        }

        // ---- transpose epilogue: 4 chunks of 8 output rows ----
        #pragma unroll 1
        for (int c = 0; c < 4; ++c) {
            if (mychunk == c) {
                #pragma unroll
                for (int q = 0; q < 4; ++q) {
                    #pragma unroll
                    for (int g = 0; g < 4; ++g) {
                        f32x4 v = {accb[g][0][q] + bb, accb[g][1][q] + bb,
                                   accb[g][2][q] + bb, accb[g][3][q] + bb};
                        *reinterpret_cast<f32x4*>(
                            &s_out[((yqb + q) * 16 + m) * 36 + xb0 + g * 4]) = v;
                    }
                }
            }
            __syncthreads();
            // read + contiguous store: 128 rows (8 yq x 16 ch) x 32 x-cols
            {
                const int li = tid & 7;        // 8 lanes x f32x4 = 32 x-cols
                const int r0 = tid >> 3;       // 32 rows per pass
                #pragma unroll
                for (int p = 0; p < 4; ++p) {
                    int row = p * 32 + r0;     // = yq*16 + ch
                    int yq = row >> 4, ch = row & 15;
                    int gy = Y0 + c * 8 + yq;
                    int gx = X0 + (li >> 2) * 32 + t * 16 + (li & 3) * 4;
                    if (gy < 252 && gx < 252) {
                        f32x4 v = *reinterpret_cast<const f32x4*>(&s_out[row * 36 + li * 4]);
                        *reinterpret_cast<f32x4*>(
                            out + (size_t)n * 16 * 63504 + (size_t)ch * 63504 +
                            (size_t)gy * 252 + gx) = v;
                    }
                }
            }
            __syncthreads();
        }
    }
}

extern "C" void kernel_launch(void* const* d_in, const int* in_sizes, int n_in,
                              void* d_out, int out_size, void* d_ws, size_t ws_size,
                              hipStream_t stream) {
    const float* x    = (const float*)d_in[0];  // (64,6,256,256)
    const float* w    = (const float*)d_in[1];  // (10,6,5,5)
    const float* bias = (const float*)d_in[2];  // (1,16,1,1)
    float* out = (float*)d_out;                 // (64,16,252,252)
    unsigned short* Bw = (unsigned short*)d_ws; // 4096 halves (8 KB) MFMA B panel

    hipLaunchKernelGGL(prep_B, dim3(16), dim3(256), 0, stream, w, Bw);
    dim3 grid(4, 8, 64);
    hipLaunchKernelGGL(c3_mfma, grid, dim3(256), 0, stream, x, Bw, bias, out);
}

// Round 9
// 131.272 us; speedup vs baseline: 5.5257x; 1.3635x over previous
//
#include <hip/hip_runtime.h>
#include <hip/hip_fp16.h>

typedef _Float16 f16x8 __attribute__((ext_vector_type(8)));
typedef float f32x4 __attribute__((ext_vector_type(4)));

// LeNet C3 connection table: input channel ii feeds CONN[ii][j] with weight[j][ii].
__device__ constexpr int CONN[6][10] = {
    {0, 4, 5, 6, 9, 10, 11, 12, 14, 15},
    {0, 1, 5, 6, 7, 10, 11, 12, 13, 15},
    {0, 1, 2, 6, 7, 8, 11, 13, 14, 15},
    {1, 2, 3, 6, 7, 8, 9, 12, 14, 15},
    {2, 3, 4, 7, 8, 9, 10, 12, 13, 15},
    {3, 4, 5, 8, 9, 10, 11, 13, 14, 15}};

__device__ constexpr int CNT[16] = {3,3,3,3,3,3,4,4,4,4,4,4,4,4,4,6};

__device__ __forceinline__ f16x8 u4_to_h8(uint4 u) { f16x8 r; __builtin_memcpy(&r, &u, 16); return r; }

// Weight A-panel in MFMA A-fragment order (M=16 channels, K'=320 over 10 MFMAs):
// Wp[(ks*64 + lane)*8 + j] = w_full[ch=lane&15][ii(kb,ks)][r(ks)][kx=j]
//   ks 0..4: ii = 2*kb, r = ks   (range A)
//   ks 5..9: ii = 2*kb+1, r = ks-5 (range B)
//   kb==3 or j>4 -> 0 (dummy k-slots; matching B-frags read garbage harmlessly)
__global__ void prep_A(const float* __restrict__ w, unsigned short* __restrict__ Wp) {
    int t = blockIdx.x * 256 + threadIdx.x;   // half index 0..5119
    if (t >= 5120) return;
    int j = t & 7, lane = (t >> 3) & 63, ks = t >> 9;
    int ch = lane & 15, kb = lane >> 4;
    float val = 0.f;
    if (kb < 3 && j < 5) {
        int ii = 2 * kb + (ks >= 5 ? 1 : 0);
        int r  = (ks >= 5) ? ks - 5 : ks;
        for (int jj = 0; jj < 10; ++jj)
            if (CONN[ii][jj] == ch) val = w[jj * 150 + ii * 25 + r * 5 + j];
    }
    __half h = __float2half(val);
    unsigned short u; __builtin_memcpy(&u, &h, 2);
    Wp[t] = u;
}

// Block: 64x x 30y tile, 4 waves (wave wv: x-strip [X0+16wv, +16)).
// C layout: col = lane&15 = x (16 consecutive), rows = channels -> contiguous
// 64B store segments, NO epilogue barriers. B-window frags roll over y: 2 new
// frags per y (ranges A/B), 3 aligned ds_read_b64 + per-lane funnel shift each.
__global__ __launch_bounds__(256, 4) void c3_mfma(
    const float* __restrict__ x, const unsigned short* __restrict__ Wp,
    const float* __restrict__ bias, float* __restrict__ out)
{
    __shared__ char s_raw[6 * 36 * 152];   // 32832 B; rows 0..34 used, pitch 152

    const int tid = threadIdx.x;
    // 1D grid + XCD chunk swizzle: 2304 blocks, 288/XCD = 8 whole images/XCD.
    int bid = blockIdx.x;
    int id = (bid & 7) * 288 + (bid >> 3);
    const int bx = id & 3;
    const int by = (id >> 2) % 9;
    const int n  = id / 36;
    const int X0 = bx * 64;
    const int Y0 = by * 30;
    const float* xin = x + (size_t)n * 6 * 65536;

    // ---- stage 6ch x 35row x 72col f32 -> fp16 LDS (18 uint2 per row) ----
    for (int i = tid; i < 6 * 35 * 18; i += 256) {
        int c4  = i % 18;
        int t   = i / 18;
        int row = t % 35;
        int ch  = t / 35;
        int gr  = Y0 + row; if (gr > 255) gr = 255;   // OOB rows feed only discarded outputs
        int gc4 = (X0 >> 2) + c4; if (gc4 > 63) gc4 = 63;
        float4 v = *reinterpret_cast<const float4*>(xin + (size_t)ch * 65536 + gr * 256 + gc4 * 4);
        __half2 lo = __floats2half2_rn(v.x, v.y);
        __half2 hi = __floats2half2_rn(v.z, v.w);
        uint2 u; __builtin_memcpy(&u.x, &lo, 4); __builtin_memcpy(&u.y, &hi, 4);
        *reinterpret_cast<uint2*>(s_raw + (ch * 36 + row) * 152 + c4 * 8) = u;
    }
    __syncthreads();

    const int lane = tid & 63;
    const int wv   = tid >> 6;
    const int nn   = lane & 15;   // B-col = x offset within strip; C-col = x
    const int kb   = lane >> 4;   // k-block; C rows = ch = kb*4+q

    // ---- weight A-frags (L2-hot, 16B/lane) ----
    f16x8 W[10];
    const uint4* wp4 = reinterpret_cast<const uint4*>(Wp);
    #pragma unroll
    for (int ks = 0; ks < 10; ++ks) W[ks] = u4_to_h8(wp4[ks * 64 + lane]);

    // ---- lane constants for window frag loads ----
    const int iiA = (kb < 3) ? 2 * kb : 0;            // kb3: dummy (zero weights)
    const int winoff = (32 * wv + 2 * nn) & ~7;       // 8B-aligned window base
    const bool hiSel = (nn & 2) != 0;                 // dword-level shift
    const unsigned shb = (unsigned)((nn & 1) * 16);   // bit-level shift
    const int rowA0 = iiA * 36 * 152 + winoff;        // byte addr of (iiA, row 0)

    auto loadf = [&](int a) -> f16x8 {
        uint2 r0 = *reinterpret_cast<const uint2*>(s_raw + a);
        uint2 r1 = *reinterpret_cast<const uint2*>(s_raw + a + 8);
        uint2 r2 = *reinterpret_cast<const uint2*>(s_raw + a + 16);
        unsigned d0 = r0.x, d1 = r0.y, d2 = r1.x, d3 = r1.y, d4 = r2.x, d5 = r2.y;
        unsigned e0 = hiSel ? d1 : d0;
        unsigned e1 = hiSel ? d2 : d1;
        unsigned e2 = hiSel ? d3 : d2;
        unsigned e3 = hiSel ? d4 : d3;
        unsigned e4 = hiSel ? d5 : d4;
        unsigned o0 = (unsigned)((((unsigned long long)e1 << 32) | e0) >> shb);
        unsigned o1 = (unsigned)((((unsigned long long)e2 << 32) | e1) >> shb);
        unsigned o2 = (unsigned)((((unsigned long long)e3 << 32) | e2) >> shb);
        unsigned o3 = (unsigned)((((unsigned long long)e4 << 32) | e3) >> shb);
        return u4_to_h8(make_uint4(o0, o1, o2, o3));
    };

    // ---- prologue: rows 0..4 for both ranges (range B at +36*152 bytes) ----
    f16x8 A0 = loadf(rowA0 + 0 * 152), A1 = loadf(rowA0 + 1 * 152),
          A2 = loadf(rowA0 + 2 * 152), A3 = loadf(rowA0 + 3 * 152),
          A4 = loadf(rowA0 + 4 * 152);
    f16x8 B0 = loadf(rowA0 + 5472 + 0 * 152), B1 = loadf(rowA0 + 5472 + 1 * 152),
          B2 = loadf(rowA0 + 5472 + 2 * 152), B3 = loadf(rowA0 + 5472 + 3 * 152),
          B4 = loadf(rowA0 + 5472 + 4 * 152);
    int aN = rowA0 + 5 * 152;                        // next load: row y+5

    // ---- store bookkeeping ----
    const int gx = X0 + wv * 16 + nn;
    const bool xok = gx < 252;
    float bb[4];
    #pragma unroll
    for (int q = 0; q < 4; ++q) {
        int ch = kb * 4 + q;
        bb[q] = bias[ch] * (float)CNT[ch];
    }
    float* const op0 = out + (size_t)n * 16 * 63504 + (size_t)(kb * 4) * 63504 + gx;
    int yoff = Y0 * 252;
    int gy = Y0;

#define PHASE(a0,a1,a2,a3,a4,b0,b1,b2,b3,b4)                                   \
    {                                                                          \
        f32x4 acc = {bb[0], bb[1], bb[2], bb[3]};                              \
        acc = __builtin_amdgcn_mfma_f32_16x16x32_f16(W[0], a0, acc, 0, 0, 0);  \
        acc = __builtin_amdgcn_mfma_f32_16x16x32_f16(W[1], a1, acc, 0, 0, 0);  \
        acc = __builtin_amdgcn_mfma_f32_16x16x32_f16(W[2], a2, acc, 0, 0, 0);  \
        acc = __builtin_amdgcn_mfma_f32_16x16x32_f16(W[3], a3, acc, 0, 0, 0);  \
        acc = __builtin_amdgcn_mfma_f32_16x16x32_f16(W[4], a4, acc, 0, 0, 0);  \
        acc = __builtin_amdgcn_mfma_f32_16x16x32_f16(W[5], b0, acc, 0, 0, 0);  \
        acc = __builtin_amdgcn_mfma_f32_16x16x32_f16(W[6], b1, acc, 0, 0, 0);  \
        acc = __builtin_amdgcn_mfma_f32_16x16x32_f16(W[7], b2, acc, 0, 0, 0);  \
        acc = __builtin_amdgcn_mfma_f32_16x16x32_f16(W[8], b3, acc, 0, 0, 0);  \
        acc = __builtin_amdgcn_mfma_f32_16x16x32_f16(W[9], b4, acc, 0, 0, 0);  \
        if (gy < 252 && xok) {                                                 \
            op0[0 * 63504 + yoff] = acc[0];                                    \
            op0[1 * 63504 + yoff] = acc[1];                                    \
            op0[2 * 63504 + yoff] = acc[2];                                    \
            op0[3 * 63504 + yoff] = acc[3];                                    \
        }                                                                      \
        ++gy; yoff += 252;                                                     \
        a0 = loadf(aN); b0 = loadf(aN + 5472); aN += 152;                      \
    }

    #pragma unroll 1
    for (int g = 0; g < 6; ++g) {        // 6 groups x 5 phases = 30 y rows
        PHASE(A0, A1, A2, A3, A4, B0, B1, B2, B3, B4)
        PHASE(A1, A2, A3, A4, A0, B1, B2, B3, B4, B0)
        PHASE(A2, A3, A4, A0, A1, B2, B3, B4, B0, B1)
        PHASE(A3, A4, A0, A1, A2, B3, B4, B0, B1, B2)
        PHASE(A4, A0, A1, A2, A3, B4, B0, B1, B2, B3)
    }
#undef PHASE
}

extern "C" void kernel_launch(void* const* d_in, const int* in_sizes, int n_in,
                              void* d_out, int out_size, void* d_ws, size_t ws_size,
                              hipStream_t stream) {
    const float* x    = (const float*)d_in[0];  // (64,6,256,256)
    const float* w    = (const float*)d_in[1];  // (10,6,5,5)
    const float* bias = (const float*)d_in[2];  // (1,16,1,1)
    float* out = (float*)d_out;                 // (64,16,252,252)
    unsigned short* Wp = (unsigned short*)d_ws; // 5120 halves (10 KB) A panel

    hipLaunchKernelGGL(prep_A, dim3(20), dim3(256), 0, stream, w, Wp);
    hipLaunchKernelGGL(c3_mfma, dim3(2304), dim3(256), 0, stream, x, Wp, bias, out);
}

// Round 10
// 129.155 us; speedup vs baseline: 5.6163x; 1.0164x over previous
//
#include <hip/hip_runtime.h>
#include <hip/hip_fp16.h>

typedef _Float16 f16x8 __attribute__((ext_vector_type(8)));
typedef float f32x4 __attribute__((ext_vector_type(4)));

// LeNet C3 connection table: input channel ii feeds CONN[ii][j] with weight[j][ii].
__device__ constexpr int CONN[6][10] = {
    {0, 4, 5, 6, 9, 10, 11, 12, 14, 15},
    {0, 1, 5, 6, 7, 10, 11, 12, 13, 15},
    {0, 1, 2, 6, 7, 8, 11, 13, 14, 15},
    {1, 2, 3, 6, 7, 8, 9, 12, 14, 15},
    {2, 3, 4, 7, 8, 9, 10, 12, 13, 15},
    {3, 4, 5, 8, 9, 10, 11, 13, 14, 15}};

__device__ constexpr int CNT[16] = {3,3,3,3,3,3,4,4,4,4,4,4,4,4,4,6};

__device__ __forceinline__ f16x8 u4_to_h8(uint4 u) { f16x8 r; __builtin_memcpy(&r, &u, 16); return r; }

// Weight A-panel in MFMA A-fragment order (M=16 channels, K'=320 over 10 MFMAs):
// Wp[(ks*64 + lane)*8 + j] = w_full[ch=lane&15][ii(kb,ks)][r(ks)][kx=j]
//   ks 0..4: ii = 2*kb, r = ks   (range A)
//   ks 5..9: ii = 2*kb+1, r = ks-5 (range B)
//   kb==3 or j>4 -> 0 (dummy k-slots)
__global__ void prep_A(const float* __restrict__ w, unsigned short* __restrict__ Wp) {
    int t = blockIdx.x * 256 + threadIdx.x;   // half index 0..5119
    if (t >= 5120) return;
    int j = t & 7, lane = (t >> 3) & 63, ks = t >> 9;
    int ch = lane & 15, kb = lane >> 4;
    float val = 0.f;
    if (kb < 3 && j < 5) {
        int ii = 2 * kb + (ks >= 5 ? 1 : 0);
        int r  = (ks >= 5) ? ks - 5 : ks;
        for (int jj = 0; jj < 10; ++jj)
            if (CONN[ii][jj] == ch) val = w[jj * 150 + ii * 25 + r * 5 + j];
    }
    __half h = __float2half(val);
    unsigned short u; __builtin_memcpy(&u, &h, 2);
    Wp[t] = u;
}

// Block: 64x x 30y tile, 4 waves (wave wv: x-strip [X0+16wv, +16)).
// C layout: col = lane&15 = x (16 consecutive) -> contiguous 64B store
// segments, no epilogue barriers. Window frags roll over y (2 new per y);
// loads are dword-aligned + v_alignbit funnel (no dword-select cndmasks).
// Two independent 5-MFMA chains (range A / range B) for ILP.
__global__ __launch_bounds__(256, 4) void c3_mfma(
    const float* __restrict__ x, const unsigned short* __restrict__ Wp,
    const float* __restrict__ bias, float* __restrict__ out)
{
    __shared__ char s_raw[6 * 35 * 152];   // 31920 B; pitch 152 B = 38 dw

    const int tid = threadIdx.x;
    // 1D grid + XCD chunk swizzle: 2304 blocks, 288/XCD = 8 whole images/XCD.
    int bid = blockIdx.x;
    int id = (bid & 7) * 288 + (bid >> 3);
    const int bx = id & 3;
    const int by = (id >> 2) % 9;
    const int n  = id / 36;
    const int X0 = bx * 64;
    const int Y0 = by * 30;
    const float* xin = x + (size_t)n * 6 * 65536;

    // ---- stage 6ch x 35row x 72col f32 -> fp16 LDS (18 uint2 per row) ----
    for (int i = tid; i < 6 * 35 * 18; i += 256) {
        int c4  = i % 18;
        int t   = i / 18;
        int row = t % 35;
        int ch  = t / 35;
        int gr  = Y0 + row; if (gr > 255) gr = 255;   // OOB rows feed only discarded outputs
        int gc4 = (X0 >> 2) + c4; if (gc4 > 63) gc4 = 63;
        float4 v = *reinterpret_cast<const float4*>(xin + (size_t)ch * 65536 + gr * 256 + gc4 * 4);
        __half2 lo = __floats2half2_rn(v.x, v.y);
        __half2 hi = __floats2half2_rn(v.z, v.w);
        uint2 u; __builtin_memcpy(&u.x, &lo, 4); __builtin_memcpy(&u.y, &hi, 4);
        *reinterpret_cast<uint2*>(s_raw + (ch * 35 + row) * 152 + c4 * 8) = u;
    }
    __syncthreads();

    const unsigned* s_dw = reinterpret_cast<const unsigned*>(s_raw);
    const int lane = tid & 63;
    const int wv   = tid >> 6;
    const int nn   = lane & 15;   // B-col = x offset within strip; C-col = x
    const int kb   = lane >> 4;   // k-block; C rows = ch = kb*4+q

    // ---- weight A-frags (L2-hot, 16B/lane) ----
    f16x8 W[10];
    const uint4* wp4 = reinterpret_cast<const uint4*>(Wp);
    #pragma unroll
    for (int ks = 0; ks < 10; ++ks) W[ks] = u4_to_h8(wp4[ks * 64 + lane]);

    // ---- lane constants for window frag loads ----
    const int iiA = (kb < 3) ? 2 * kb : 0;             // kb3: dummy (zero weights)
    const int dwoff = (32 * wv + 2 * nn) >> 2;         // dword base within row
    const unsigned shb = (unsigned)((nn & 1) * 16);    // 16-bit funnel shift

    auto loadf = [&](int dwaddr) -> f16x8 {
        unsigned e0 = s_dw[dwaddr],     e1 = s_dw[dwaddr + 1],
                 e2 = s_dw[dwaddr + 2], e3 = s_dw[dwaddr + 3],
                 e4 = s_dw[dwaddr + 4];
        unsigned o0 = (unsigned)((((unsigned long long)e1 << 32) | e0) >> shb);
        unsigned o1 = (unsigned)((((unsigned long long)e2 << 32) | e1) >> shb);
        unsigned o2 = (unsigned)((((unsigned long long)e3 << 32) | e2) >> shb);
        unsigned o3 = (unsigned)((((unsigned long long)e4 << 32) | e3) >> shb);
        return u4_to_h8(make_uint4(o0, o1, o2, o3));
    };

    // ---- prologue: rows 0..4 for both ranges (range B at +35*38 dwords) ----
    const int r0dw = iiA * 35 * 38 + dwoff;
    f16x8 A0 = loadf(r0dw + 0 * 38), A1 = loadf(r0dw + 1 * 38),
          A2 = loadf(r0dw + 2 * 38), A3 = loadf(r0dw + 3 * 38),
          A4 = loadf(r0dw + 4 * 38);
    f16x8 B0 = loadf(r0dw + 1330 + 0 * 38), B1 = loadf(r0dw + 1330 + 1 * 38),
          B2 = loadf(r0dw + 1330 + 2 * 38), B3 = loadf(r0dw + 1330 + 3 * 38),
          B4 = loadf(r0dw + 1330 + 4 * 38);
    int aN = r0dw + 5 * 38;                        // next load: row y+5

    // ---- store bookkeeping ----
    const int gx = X0 + wv * 16 + nn;
    const bool xok = gx < 252;
    float bb[4];
    #pragma unroll
    for (int q = 0; q < 4; ++q) {
        int ch = kb * 4 + q;
        bb[q] = bias[ch] * (float)CNT[ch];
    }
    float* const op0 = out + (size_t)n * 16 * 63504 + (size_t)(kb * 4) * 63504 + gx;
    int yoff = Y0 * 252;
    int gy = Y0;

#define PHASE(a0,a1,a2,a3,a4,b0,b1,b2,b3,b4)                                    \
    {                                                                           \
        f32x4 accA = {bb[0], bb[1], bb[2], bb[3]};                              \
        f32x4 accB = {0.f, 0.f, 0.f, 0.f};                                      \
        accA = __builtin_amdgcn_mfma_f32_16x16x32_f16(W[0], a0, accA, 0, 0, 0); \
        accB = __builtin_amdgcn_mfma_f32_16x16x32_f16(W[5], b0, accB, 0, 0, 0); \
        a0 = loadf(aN); b0 = loadf(aN + 1330); aN += 38;                        \
        accA = __builtin_amdgcn_mfma_f32_16x16x32_f16(W[1], a1, accA, 0, 0, 0); \
        accB = __builtin_amdgcn_mfma_f32_16x16x32_f16(W[6], b1, accB, 0, 0, 0); \
        accA = __builtin_amdgcn_mfma_f32_16x16x32_f16(W[2], a2, accA, 0, 0, 0); \
        accB = __builtin_amdgcn_mfma_f32_16x16x32_f16(W[7], b2, accB, 0, 0, 0); \
        accA = __builtin_amdgcn_mfma_f32_16x16x32_f16(W[3], a3, accA, 0, 0, 0); \
        accB = __builtin_amdgcn_mfma_f32_16x16x32_f16(W[8], b3, accB, 0, 0, 0); \
        accA = __builtin_amdgcn_mfma_f32_16x16x32_f16(W[4], a4, accA, 0, 0, 0); \
        accB = __builtin_amdgcn_mfma_f32_16x16x32_f16(W[9], b4, accB, 0, 0, 0); \
        if (gy < 252 && xok) {                                                  \
            f32x4 acc = accA + accB;                                            \
            op0[0 * 63504 + yoff] = acc[0];                                     \
            op0[1 * 63504 + yoff] = acc[1];                                     \
            op0[2 * 63504 + yoff] = acc[2];                                     \
            op0[3 * 63504 + yoff] = acc[3];                                     \
        }                                                                       \
        ++gy; yoff += 252;                                                      \
    }

    #pragma unroll 1
    for (int g = 0; g < 6; ++g) {        // 6 groups x 5 phases = 30 y rows
        PHASE(A0, A1, A2, A3, A4, B0, B1, B2, B3, B4)
        PHASE(A1, A2, A3, A4, A0, B1, B2, B3, B4, B0)
        PHASE(A2, A3, A4, A0, A1, B2, B3, B4, B0, B1)
        PHASE(A3, A4, A0, A1, A2, B3, B4, B0, B1, B2)
        PHASE(A4, A0, A1, A2, A3, B4, B0, B1, B2, B3)
    }
#undef PHASE
}

extern "C" void kernel_launch(void* const* d_in, const int* in_sizes, int n_in,
                              void* d_out, int out_size, void* d_ws, size_t ws_size,
                              hipStream_t stream) {
    const float* x    = (const float*)d_in[0];  // (64,6,256,256)
    const float* w    = (const float*)d_in[1];  // (10,6,5,5)
    const float* bias = (const float*)d_in[2];  // (1,16,1,1)
    float* out = (float*)d_out;                 // (64,16,252,252)
    unsigned short* Wp = (unsigned short*)d_ws; // 5120 halves (10 KB) A panel

    hipLaunchKernelGGL(prep_A, dim3(20), dim3(256), 0, stream, w, Wp);
    hipLaunchKernelGGL(c3_mfma, dim3(2304), dim3(256), 0, stream, x, Wp, bias, out);
}

// Round 11
// 110.267 us; speedup vs baseline: 6.5783x; 1.1713x over previous
//
#include <hip/hip_runtime.h>
#include <hip/hip_fp16.h>

typedef _Float16 f16x8 __attribute__((ext_vector_type(8)));
typedef float f32x4 __attribute__((ext_vector_type(4)));

// LeNet C3 connection table: input channel ii feeds CONN[ii][j] with weight[j][ii].
__device__ constexpr int CONN[6][10] = {
    {0, 4, 5, 6, 9, 10, 11, 12, 14, 15},
    {0, 1, 5, 6, 7, 10, 11, 12, 13, 15},
    {0, 1, 2, 6, 7, 8, 11, 13, 14, 15},
    {1, 2, 3, 6, 7, 8, 9, 12, 14, 15},
    {2, 3, 4, 7, 8, 9, 10, 12, 13, 15},
    {3, 4, 5, 8, 9, 10, 11, 13, 14, 15}};

__device__ constexpr int CNT[16] = {3,3,3,3,3,3,4,4,4,4,4,4,4,4,4,6};

__device__ __forceinline__ f16x8 u4_to_h8(uint4 u) { f16x8 r; __builtin_memcpy(&r, &u, 16); return r; }

#define PITCH_DW 132           // dwords per LDS row (264 halves, 8B-aligned rows)
#define PLANE_DW (17 * 132)    // 17-row plane (16 staged + 1 pad): kb bank spread

// Weight A-panel in MFMA A-fragment order (M=16 channels, K'=320 over 10 MFMAs):
// Wp[(ks*64 + lane)*8 + j] = w_full[ch=lane&15][ii(kb,ks)][r(ks)][kx=j]
//   ks 0..4: ii = 2*kb, r = ks   (range A); ks 5..9: ii = 2*kb+1, r = ks-5 (range B)
//   kb==3 or j>4 -> 0 (dummy k-slots)
__global__ void prep_A(const float* __restrict__ w, unsigned short* __restrict__ Wp) {
    int t = blockIdx.x * 256 + threadIdx.x;   // half index 0..5119
    if (t >= 5120) return;
    int j = t & 7, lane = (t >> 3) & 63, ks = t >> 9;
    int ch = lane & 15, kb = lane >> 4;
    float val = 0.f;
    if (kb < 3 && j < 5) {
        int ii = 2 * kb + (ks >= 5 ? 1 : 0);
        int r  = (ks >= 5) ? ks - 5 : ks;
        for (int jj = 0; jj < 10; ++jj)
            if (CONN[ii][jj] == ch) val = w[jj * 150 + ii * 25 + r * 5 + j];
    }
    __half h = __float2half(val);
    unsigned short u; __builtin_memcpy(&u, &h, 2);
    Wp[t] = u;
}

// Block: FULL-WIDTH 256x x 12y tile, 4 waves. At strip-step t, the 4 waves
// cover x [64t, 64t+63] -> adjacent 64B store segments of the same output
// pages at the same time; consecutive blocks sweep y sequentially per image.
// HBM write stream becomes page-ordered (the R10 binder).
__global__ __launch_bounds__(256, 3) void c3_mfma(
    const float* __restrict__ x, const unsigned short* __restrict__ Wp,
    const float* __restrict__ bias, float* __restrict__ out)
{
    __shared__ unsigned s_lds[6 * PLANE_DW];   // 53856 B

    const int tid = threadIdx.x;
    // 1344 blocks = 64 n x 21 y-tiles; bijective XCD chunking (1344 = 8*168).
    const int id = (blockIdx.x & 7) * 168 + (blockIdx.x >> 3);
    const int by = id % 21;
    const int n  = id / 21;
    const int Y0 = by * 12;
    const float* xin = x + (size_t)n * 6 * 65536;

    // ---- stage 6ch x 16row x 256col f32 -> fp16 (all pow-2 index math) ----
    #pragma unroll 4
    for (int it = 0; it < 24; ++it) {
        int i   = tid + it * 256;
        int c4  = i & 63;          // float4 column
        int row = (i >> 6) & 15;
        int ch  = i >> 10;
        float4 v = *reinterpret_cast<const float4*>(
            xin + (size_t)ch * 65536 + (size_t)(Y0 + row) * 256 + c4 * 4);
        __half2 lo = __floats2half2_rn(v.x, v.y);
        __half2 hi = __floats2half2_rn(v.z, v.w);
        uint2 u; __builtin_memcpy(&u.x, &lo, 4); __builtin_memcpy(&u.y, &hi, 4);
        *reinterpret_cast<uint2*>(&s_lds[ch * PLANE_DW + row * PITCH_DW + c4 * 2]) = u;
    }
    // halo cols 256-259 = zeros (feed only masked x>=252 outputs)
    if (tid < 96) {
        int ch = tid >> 4, row = tid & 15;
        *reinterpret_cast<uint2*>(&s_lds[ch * PLANE_DW + row * PITCH_DW + 128]) =
            make_uint2(0u, 0u);
    }
    __syncthreads();

    const int lane = tid & 63;
    const int wv   = tid >> 6;
    const int nn   = lane & 15;   // B-col = x offset within strip; C-col = x
    const int kb   = lane >> 4;   // k-block; C rows = ch = kb*4+q

    // ---- weight A-frags (L2-hot, 16B/lane) ----
    f16x8 W[10];
    const uint4* wp4 = reinterpret_cast<const uint4*>(Wp);
    #pragma unroll
    for (int ks = 0; ks < 10; ++ks) W[ks] = u4_to_h8(wp4[ks * 64 + lane]);

    const int iiA = (kb < 3) ? 2 * kb : 0;             // kb3: dummy (zero weights)
    const unsigned shb = (unsigned)((nn & 1) * 16);    // 16-bit funnel shift

    auto loadf = [&](int dwaddr) -> f16x8 {
        unsigned e0 = s_lds[dwaddr],     e1 = s_lds[dwaddr + 1],
                 e2 = s_lds[dwaddr + 2], e3 = s_lds[dwaddr + 3],
                 e4 = s_lds[dwaddr + 4];
        unsigned o0 = (unsigned)((((unsigned long long)e1 << 32) | e0) >> shb);
        unsigned o1 = (unsigned)((((unsigned long long)e2 << 32) | e1) >> shb);
        unsigned o2 = (unsigned)((((unsigned long long)e3 << 32) | e2) >> shb);
        unsigned o3 = (unsigned)((((unsigned long long)e4 << 32) | e3) >> shb);
        return u4_to_h8(make_uint4(o0, o1, o2, o3));
    };

    float bb[4];
    #pragma unroll
    for (int q = 0; q < 4; ++q) {
        int ch = kb * 4 + q;
        bb[q] = bias[ch] * (float)CNT[ch];
    }

#define PHASE(a0,a1,a2,a3,a4,b0,b1,b2,b3,b4)                                    \
    {                                                                           \
        f32x4 accA = {bb[0], bb[1], bb[2], bb[3]};                              \
        f32x4 accB = {0.f, 0.f, 0.f, 0.f};                                      \
        accA = __builtin_amdgcn_mfma_f32_16x16x32_f16(W[0], a0, accA, 0, 0, 0); \
        accB = __builtin_amdgcn_mfma_f32_16x16x32_f16(W[5], b0, accB, 0, 0, 0); \
        a0 = loadf(aN); b0 = loadf(aN + 2244); aN += PITCH_DW;                  \
        accA = __builtin_amdgcn_mfma_f32_16x16x32_f16(W[1], a1, accA, 0, 0, 0); \
        accB = __builtin_amdgcn_mfma_f32_16x16x32_f16(W[6], b1, accB, 0, 0, 0); \
        accA = __builtin_amdgcn_mfma_f32_16x16x32_f16(W[2], a2, accA, 0, 0, 0); \
        accB = __builtin_amdgcn_mfma_f32_16x16x32_f16(W[7], b2, accB, 0, 0, 0); \
        accA = __builtin_amdgcn_mfma_f32_16x16x32_f16(W[3], a3, accA, 0, 0, 0); \
        accB = __builtin_amdgcn_mfma_f32_16x16x32_f16(W[8], b3, accB, 0, 0, 0); \
        accA = __builtin_amdgcn_mfma_f32_16x16x32_f16(W[4], a4, accA, 0, 0, 0); \
        accB = __builtin_amdgcn_mfma_f32_16x16x32_f16(W[9], b4, accB, 0, 0, 0); \
        if (xok) {                                                              \
            f32x4 acc = accA + accB;                                            \
            op0[0 * 63504 + yoff] = acc[0];                                     \
            op0[1 * 63504 + yoff] = acc[1];                                     \
            op0[2 * 63504 + yoff] = acc[2];                                     \
            op0[3 * 63504 + yoff] = acc[3];                                     \
        }                                                                       \
        yoff += 252;                                                            \
    }

    #pragma unroll 1
    for (int t = 0; t < 4; ++t) {          // strip-step: waves cover x[64t,64t+63]
        const int gx = 64 * t + 16 * wv + nn;
        const bool xok = gx < 252;
        const int baseA = iiA * PLANE_DW + (gx >> 1);
        // prologue: rows 0..4 of ranges A (plane iiA) and B (plane iiA+1)
        f16x8 A0 = loadf(baseA + 0 * PITCH_DW), A1 = loadf(baseA + 1 * PITCH_DW),
              A2 = loadf(baseA + 2 * PITCH_DW), A3 = loadf(baseA + 3 * PITCH_DW),
              A4 = loadf(baseA + 4 * PITCH_DW);
        f16x8 B0 = loadf(baseA + 2244 + 0 * PITCH_DW), B1 = loadf(baseA + 2244 + 1 * PITCH_DW),
              B2 = loadf(baseA + 2244 + 2 * PITCH_DW), B3 = loadf(baseA + 2244 + 3 * PITCH_DW),
              B4 = loadf(baseA + 2244 + 4 * PITCH_DW);
        int aN = baseA + 5 * PITCH_DW;

        float* const op0 = out + (size_t)n * 16 * 63504 + (size_t)(kb * 4) * 63504 + gx;
        int yoff = Y0 * 252;

        PHASE(A0, A1, A2, A3, A4, B0, B1, B2, B3, B4)
        PHASE(A1, A2, A3, A4, A0, B1, B2, B3, B4, B0)
        PHASE(A2, A3, A4, A0, A1, B2, B3, B4, B0, B1)
        PHASE(A3, A4, A0, A1, A2, B3, B4, B0, B1, B2)
        PHASE(A4, A0, A1, A2, A3, B4, B0, B1, B2, B3)
        PHASE(A0, A1, A2, A3, A4, B0, B1, B2, B3, B4)
        PHASE(A1, A2, A3, A4, A0, B1, B2, B3, B4, B0)
        PHASE(A2, A3, A4, A0, A1, B2, B3, B4, B0, B1)
        PHASE(A3, A4, A0, A1, A2, B3, B4, B0, B1, B2)
        PHASE(A4, A0, A1, A2, A3, B4, B0, B1, B2, B3)
        PHASE(A0, A1, A2, A3, A4, B0, B1, B2, B3, B4)
        PHASE(A1, A2, A3, A4, A0, B1, B2, B3, B4, B0)
    }
#undef PHASE
}

extern "C" void kernel_launch(void* const* d_in, const int* in_sizes, int n_in,
                              void* d_out, int out_size, void* d_ws, size_t ws_size,
                              hipStream_t stream) {
    const float* x    = (const float*)d_in[0];  // (64,6,256,256)
    const float* w    = (const float*)d_in[1];  // (10,6,5,5)
    const float* bias = (const float*)d_in[2];  // (1,16,1,1)
    float* out = (float*)d_out;                 // (64,16,252,252)
    unsigned short* Wp = (unsigned short*)d_ws; // 5120 halves (10 KB) A panel

    hipLaunchKernelGGL(prep_A, dim3(20), dim3(256), 0, stream, w, Wp);
    hipLaunchKernelGGL(c3_mfma, dim3(1344), dim3(256), 0, stream, x, Wp, bias, out);
}